// Round 15
// baseline (21138.896 us; speedup 1.0000x reference)
//
#include <hip/hip_runtime.h>
#include <hip/hip_bf16.h>

// QLSTM (S=512,B=256,D=256,H=256,E=512), f32 in/out, bf16 MFMA internals.
// Algebraic form: M = Wq^T Wk, U_a = W_a @ Wv precomputed once (init).
//   scores = (comb @ M) @ comb^T ; a2 = P @ comb ; gate_a = a2 @ U_a^T + b_a
// r15: NSTEP=8 steps fused per dispatch (64 dispatches). Between fused steps:
// flag-tree barrier (64 WGs, relaxed sc1 flags, vmcnt drain, NO fences).
// Cross-step tensors comb/combT: sc1 8B stores (write-through LLC) + sc0sc1
// 16B batched loads (L1/L2 bypass) -> always fresh; MT/U/x stay plain-cached
// so L2 stays warm. Math bit-identical to r14.

typedef __hip_bfloat16 bf16;
typedef __attribute__((ext_vector_type(8))) short bf16x8;   // 8 bf16 = 4 VGPR
typedef __attribute__((ext_vector_type(4))) float f32x4;
typedef unsigned long long u64;

#define SEQ 512
#define NSTEP 8
#define BB  256
#define DD  256
#define HH  256
#define EE  512
#define NWG 64
#define QK_SCALE 0.04419417382415922f  // 1/sqrt(512)

// ws layout (bytes)
#define WS_COMB0  0          // bf16 [256][512]  step-parity 0
#define WS_COMB1  262144     // parity 1
#define WS_COMBT0 524288     // bf16 [512][256]  comb transposed, parity 0
#define WS_COMBT1 786432     // parity 1
#define WS_CX     1048576    // f32 [64 WG][1024]  lane-stable cell state
#define WS_MT     1310720    // bf16 [512][512]  MT[n][e] = M[e][n], M = Wq^T Wk
#define WS_UF     1835008    // bf16 [256][512]  Uf = Wf @ Wv
#define WS_UI     2097152
#define WS_UG     2359296
#define WS_UO     2621440
#define WS_FLAGS  2883584    // u32 [64] stride 64B (arrival flags)
#define WS_REL    2887680    // u32 [8]  stride 64B (release copies)
#define WS_END    2888192

__device__ __forceinline__ float sigm(float x) { return 1.0f / (1.0f + __expf(-x)); }

__device__ __forceinline__ unsigned short f2bf_s(float f) {
  bf16 h = __float2bfloat16(f);
  return *reinterpret_cast<unsigned short*>(&h);
}
__device__ __forceinline__ u64 pack4(float a, float b, float c, float d) {
  union { unsigned short s[4]; u64 u; } x;
  x.s[0] = f2bf_s(a); x.s[1] = f2bf_s(b); x.s[2] = f2bf_s(c); x.s[3] = f2bf_s(d);
  return x.u;
}
// sc1 relaxed atomics (LLC coherence point)
__device__ __forceinline__ void sta8(void* p, u64 v) {
  __hip_atomic_store((u64*)p, v, __ATOMIC_RELAXED, __HIP_MEMORY_SCOPE_AGENT);
}
__device__ __forceinline__ unsigned lda4(const unsigned* p) {
  return __hip_atomic_load(p, __ATOMIC_RELAXED, __HIP_MEMORY_SCOPE_AGENT);
}
__device__ __forceinline__ void sta4(unsigned* p, unsigned v) {
  __hip_atomic_store(p, v, __ATOMIC_RELAXED, __HIP_MEMORY_SCOPE_AGENT);
}
// device-coherent 16B load (bypass L1+L2, read LLC)
#define LOAD16_COH(dst, addr) \
  asm volatile("global_load_dwordx4 %0, %1, off sc0 sc1" : "=v"(dst) : "v"(addr))

// flag-tree grid barrier, 64 WGs, no fences (data is sc1-coherent already)
__device__ __forceinline__ void gbar64(unsigned* flags, unsigned* rel,
                                       int wg, unsigned val) {
  asm volatile("s_waitcnt vmcnt(0)" ::: "memory");   // sc1 stores at LLC
  __syncthreads();
  const int tid = threadIdx.x;
  if (wg == NWG - 1) {
    if (tid < 64) {
      if (tid == 0) sta4(&flags[(NWG - 1) * 16], val);
      if (tid < NWG) {
        while (lda4(&flags[tid * 16]) < val) __builtin_amdgcn_s_sleep(1);
      }
    }
    __syncthreads();
    if (tid < 8) sta4(&rel[tid * 16], val);
  } else {
    if (tid == 0) {
      sta4(&flags[wg * 16], val);
      while (lda4(&rel[(wg & 7) * 16]) < val) __builtin_amdgcn_s_sleep(1);
    }
  }
  __syncthreads();
}

// ---------------- init: comb0/combT0, cx=0, flags, MT, U matrices -----------
__global__ void __launch_bounds__(256) qlstm_init_kernel(
    const float* __restrict__ x,
    const float* __restrict__ Wq, const float* __restrict__ Wk, const float* __restrict__ Wv,
    const float* __restrict__ Wf, const float* __restrict__ Wi,
    const float* __restrict__ Wg, const float* __restrict__ Wo,
    char* __restrict__ wsb)
{
  const int gid = blockIdx.x * blockDim.x + threadIdx.x;   // 0..131071
  bf16* comb0  = (bf16*)(wsb + WS_COMB0);
  bf16* combT0 = (bf16*)(wsb + WS_COMBT0);
  float* cx    = (float*)(wsb + WS_CX);
  bf16* mt     = (bf16*)(wsb + WS_MT);

  if (gid < 65536) {
    const int i = gid >> 8, e = gid & 255;
    const bf16 xv = __float2bfloat16(x[i * DD + e]);       // x[t=0][i][e]
    comb0[i * EE + e] = xv;
    comb0[i * EE + 256 + e] = __float2bfloat16(0.0f);
    combT0[e * BB + i] = xv;
    combT0[(256 + e) * BB + i] = __float2bfloat16(0.0f);
  } else {
    cx[gid - 65536] = 0.0f;
  }
  if (gid < (WS_END - WS_FLAGS) / 4) ((unsigned*)(wsb + WS_FLAGS))[gid] = 0u;

  // MT[n][e] = M[e][n] = sum_j Wq[j][e] * Wk[j][n]
  #pragma unroll 1
  for (int kk = 0; kk < 2; ++kk) {
    const int o = gid + kk * 131072;        // 0..262143
    const int n = o >> 9, e = o & 511;
    float acc = 0.0f;
    #pragma unroll 4
    for (int j = 0; j < 512; ++j) acc = __builtin_fmaf(Wq[j * 512 + e], Wk[j * 512 + n], acc);
    mt[o] = __float2bfloat16(acc);
  }
  // U_a[h][e] = sum_e' W_a[h][e'] * Wv[e'][e]
  const float* srcs[4] = { Wf, Wi, Wg, Wo };
  const int offs[4] = { WS_UF, WS_UI, WS_UG, WS_UO };
  #pragma unroll 1
  for (int a = 0; a < 4; ++a) {
    bf16* U = (bf16*)(wsb + offs[a]);
    const float* W = srcs[a];
    const int h = gid >> 9, e = gid & 511;
    float acc = 0.0f;
    #pragma unroll 4
    for (int ep = 0; ep < 512; ++ep) acc = __builtin_fmaf(W[h * 512 + ep], Wv[ep * 512 + e], acc);
    U[gid] = __float2bfloat16(acc);
  }
}

// ---------------- fused 8-step kernel: 64 WGs x 1024 thr --------------------
__global__ void __launch_bounds__(1024) qlstm_step_kernel(
    const float* __restrict__ x,
    const float* __restrict__ bfv, const float* __restrict__ biv,
    const float* __restrict__ bgv, const float* __restrict__ bov,
    float* __restrict__ out, char* __restrict__ wsb, int t0, int bbase)
{
  float* cx_ws = (float*)(wsb + WS_CX);
  const bf16* mt   = (const bf16*)(wsb + WS_MT);
  const bf16* uf_b = (const bf16*)(wsb + WS_UF);
  const bf16* ui_b = (const bf16*)(wsb + WS_UI);
  const bf16* ug_b = (const bf16*)(wsb + WS_UG);
  const bf16* uo_b = (const bf16*)(wsb + WS_UO);
  unsigned* flags = (unsigned*)(wsb + WS_FLAGS);
  unsigned* rel   = (unsigned*)(wsb + WS_REL);

  const int wg   = blockIdx.x;     // 0..63
  const int s    = wg >> 2;        // strip 0..15
  const int q4   = wg & 3;         // h-quarter 0..3
  const int r0   = s * 16;
  const int tid  = threadIdx.x;
  const int wid  = tid >> 6;       // wave 0..15
  const int lane = tid & 63;
  const int l16  = lane & 15;
  const int kq   = lane >> 4;      // 0..3

  __shared__ unsigned short c_lds[16 * 520];    // comb strip (staged); later xT
  __shared__ unsigned short z_lds[16 * 520];    // z strip (bf16), batch-major
  __shared__ unsigned short a_lds[16 * 520];    // a2 strip (bf16), batch-major
  __shared__ float          s_lds[16 * 256];    // scores f32
  __shared__ unsigned short p_lds[16 * 264];    // probs bf16 (+8 pad)
  __shared__ float          g_lds[16 * 256];    // gate pre-acts
  __shared__ unsigned short ht_lds[64 * 18];    // h tile transposed [colg64][i]

  for (int k = 0; k < NSTEP; ++k) {
    const int t = t0 + k;
    const int par = t & 1;
    const bf16* comb   = (const bf16*)(wsb + (par ? WS_COMB1 : WS_COMB0));
    const bf16* combT  = (const bf16*)(wsb + (par ? WS_COMBT1 : WS_COMBT0));
    bf16* combN  = (bf16*)(wsb + (par ? WS_COMB0 : WS_COMB1));
    bf16* combTN = (bf16*)(wsb + (par ? WS_COMBT0 : WS_COMBT1));

    // ---- stage comb strip rows r0..r0+16 into LDS (coherent 16B loads)
    {
      const int row = tid >> 6, c8 = (tid & 63) * 8;
      bf16x8 cv;
      LOAD16_COH(cv, comb + (size_t)(r0 + row) * EE + c8);
      asm volatile("s_waitcnt vmcnt(0)" ::: "memory");
      *(bf16x8*)(&c_lds[row * 520 + c8]) = cv;
    }
    __syncthreads();

    // ---- Z: z = comb_strip @ M  (A = MT rows n [8-deep plain batch], B = LDS)
    #pragma unroll
    for (int h2 = 0; h2 < 2; ++h2) {
      const int n0 = (wid * 2 + h2) * 16;
      const bf16* arow = mt + (size_t)(n0 + l16) * EE;
      const unsigned short* brow = &c_lds[l16 * 520];
      f32x4 acc = {0.f, 0.f, 0.f, 0.f};
      #pragma unroll
      for (int half = 0; half < 2; ++half) {
        bf16x8 mfr[8];
        #pragma unroll
        for (int u = 0; u < 8; ++u)
          mfr[u] = *(const bf16x8*)(arow + (half * 8 + u) * 32 + kq * 8);
        #pragma unroll
        for (int u = 0; u < 8; ++u) {
          bf16x8 bf8 = *(const bf16x8*)(brow + (half * 8 + u) * 32 + kq * 8);
          acc = __builtin_amdgcn_mfma_f32_16x16x32_bf16(mfr[u], bf8, acc, 0, 0, 0);
        }
      }
      *(u64*)(&z_lds[l16 * 520 + n0 + kq * 4]) = pack4(acc[0], acc[1], acc[2], acc[3]);
    }
    __syncthreads();
    // ---- B: scores = z @ comb^T  (B operand = comb rows j, coherent batched)
    {
      const int j0 = wid * 16;
      const unsigned short* arow = &z_lds[l16 * 520];
      const bf16* brow = comb + (size_t)(j0 + l16) * EE;
      f32x4 acc = {0.f, 0.f, 0.f, 0.f};
      #pragma unroll
      for (int half = 0; half < 2; ++half) {
        bf16x8 cfr[8];
        #pragma unroll
        for (int u = 0; u < 8; ++u)
          LOAD16_COH(cfr[u], brow + (half * 8 + u) * 32 + kq * 8);
        asm volatile("s_waitcnt vmcnt(0)" ::: "memory");
        __builtin_amdgcn_sched_barrier(0);
        #pragma unroll
        for (int u = 0; u < 8; ++u) {
          bf16x8 af = *(const bf16x8*)(arow + (half * 8 + u) * 32 + kq * 8);
          acc = __builtin_amdgcn_mfma_f32_16x16x32_bf16(af, cfr[u], acc, 0, 0, 0);
        }
      }
      #pragma unroll
      for (int r = 0; r < 4; ++r)
        s_lds[(kq * 4 + r) * 256 + j0 + l16] = acc[r];
    }
    __syncthreads();
    // ---- C: softmax row i = wid
    {
      const int i = wid;
      const float4 v = *(const float4*)(&s_lds[i * 256 + lane * 4]);
      float m = fmaxf(fmaxf(v.x, v.y), fmaxf(v.z, v.w));
      #pragma unroll
      for (int off = 32; off > 0; off >>= 1) m = fmaxf(m, __shfl_xor(m, off));
      float e0 = __expf((v.x - m) * QK_SCALE);
      float e1 = __expf((v.y - m) * QK_SCALE);
      float e2 = __expf((v.z - m) * QK_SCALE);
      float e3 = __expf((v.w - m) * QK_SCALE);
      float sum = e0 + e1 + e2 + e3;
      #pragma unroll
      for (int off = 32; off > 0; off >>= 1) sum += __shfl_xor(sum, off);
      const float rinv = 1.0f / sum;
      unsigned short* pp = &p_lds[i * 264 + lane * 4];
      pp[0] = f2bf_s(e0 * rinv);
      pp[1] = f2bf_s(e1 * rinv);
      pp[2] = f2bf_s(e2 * rinv);
      pp[3] = f2bf_s(e3 * rinv);
    }
    __syncthreads();
    // ---- D: a2 = P @ comb (A = combT rows n, coherent batched; B = P LDS)
    #pragma unroll
    for (int q8 = 0; q8 < 2; ++q8) {
      const int n0 = wid * 16 + q8 * 256;
      const bf16* arow = combT + (size_t)(n0 + l16) * BB;
      const unsigned short* brow = &p_lds[l16 * 264];
      f32x4 acc = {0.f, 0.f, 0.f, 0.f};
      bf16x8 tfr[8];
      #pragma unroll
      for (int u = 0; u < 8; ++u)
        LOAD16_COH(tfr[u], arow + u * 32 + kq * 8);
      asm volatile("s_waitcnt vmcnt(0)" ::: "memory");
      __builtin_amdgcn_sched_barrier(0);
      #pragma unroll
      for (int u = 0; u < 8; ++u) {
        bf16x8 bf8 = *(const bf16x8*)(brow + u * 32 + kq * 8);
        acc = __builtin_amdgcn_mfma_f32_16x16x32_bf16(tfr[u], bf8, acc, 0, 0, 0);
      }
      *(u64*)(&a_lds[l16 * 520 + n0 + kq * 4]) = pack4(acc[0], acc[1], acc[2], acc[3]);
    }
    __syncthreads();
    // ---- E: gates (wave wid -> gate g=wid>>2, hcb=wid&3), U plain-cached
    {
      const int g   = wid >> 2;
      const int hcb = wid & 3;
      const int h0  = q4 * 64 + hcb * 16;
      const bf16* U = (g == 0) ? uf_b : (g == 1) ? ui_b : (g == 2) ? ug_b : uo_b;
      const unsigned short* arow = &a_lds[l16 * 520];
      const bf16* brow = U + (size_t)(h0 + l16) * EE;
      f32x4 acc = {0.f, 0.f, 0.f, 0.f};
      #pragma unroll
      for (int half = 0; half < 2; ++half) {
        bf16x8 ufr[8];
        #pragma unroll
        for (int u = 0; u < 8; ++u)
          ufr[u] = *(const bf16x8*)(brow + (half * 8 + u) * 32 + kq * 8);
        #pragma unroll
        for (int u = 0; u < 8; ++u) {
          bf16x8 af = *(const bf16x8*)(arow + (half * 8 + u) * 32 + kq * 8);
          acc = __builtin_amdgcn_mfma_f32_16x16x32_bf16(af, ufr[u], acc, 0, 0, 0);
        }
      }
      #pragma unroll
      for (int r = 0; r < 4; ++r)
        g_lds[wid * 256 + (kq * 4 + r) * 16 + l16] = acc[r];
    }
    __syncthreads();
    // ---- update
    {
      const int hcb2 = tid >> 8;
      const int idx  = tid & 255;
      const int i    = idx >> 4, c = idx & 15;
      const int colg = q4 * 64 + hcb2 * 16 + c;
      const float F = sigm(g_lds[(0 * 4 + hcb2) * 256 + idx] + bfv[colg]);
      const float I = sigm(g_lds[(1 * 4 + hcb2) * 256 + idx] + biv[colg]);
      const float G = tanhf(g_lds[(2 * 4 + hcb2) * 256 + idx] + bgv[colg]);
      const float O = sigm(g_lds[(3 * 4 + hcb2) * 256 + idx] + bov[colg]);
      float* cxp = cx_ws + (size_t)wg * 1024 + tid;
      const float c2 = F * (*cxp) + I * G;
      const float h  = O * tanhf(c2);
      *cxp = c2;
      out[(size_t)t * 65536 + (size_t)(r0 + i) * 256 + colg] = h;
      if (t < SEQ - 1) {
        const bf16 hb = __float2bfloat16(h);
        ht_lds[(hcb2 * 16 + c) * 18 + i] = *reinterpret_cast<const unsigned short*>(&hb);
      } else {
        out[(size_t)SEQ * 65536 + (size_t)(r0 + i) * 256 + colg] = h;           // hx tail
        out[(size_t)SEQ * 65536 + 65536 + (size_t)(r0 + i) * 256 + colg] = c2;  // cx tail
      }
    }
    __syncthreads();
    if (t < SEQ - 1) {
      // ---- combN h-part: 8B sc1 stores packed from ht_lds
      if (tid < 256) {
        const int i = tid >> 4, c4 = (tid & 15) * 4;
        union { unsigned short sv[4]; u64 u; } pk;
        #pragma unroll
        for (int j = 0; j < 4; ++j) pk.sv[j] = ht_lds[(c4 + j) * 18 + i];
        sta8(combN + (size_t)(r0 + i) * EE + 256 + q4 * 64 + c4, pk.u);
      }
      // ---- combT h-part: 64 rows x 2 x 16B (as 2x8B sc1)
      if (tid < 128) {
        const int row64 = tid >> 1, half = tid & 1;
        const int e = 256 + q4 * 64 + row64;
        sta8(combTN + (size_t)e * BB + r0 + half * 8,
             *(const u64*)(&ht_lds[row64 * 18 + half * 8]));
        sta8(combTN + (size_t)e * BB + r0 + half * 8 + 4,
             *(const u64*)(&ht_lds[row64 * 18 + half * 8 + 4]));
      }
      // ---- x-part of next comb (q4==0 WGs)
      if (q4 == 0) {
        unsigned short* xT = c_lds;              // reuse, stride 18: [256][18]
        {
          const int i2 = tid >> 6, e4 = (tid & 63) * 4;
          const float4 xf = *(const float4*)(x + ((size_t)(t + 1) * BB + r0 + i2) * DD + e4);
          const u64 p = pack4(xf.x, xf.y, xf.z, xf.w);
          const unsigned short* ps = (const unsigned short*)&p;
          xT[(e4 + 0) * 18 + i2] = ps[0];
          xT[(e4 + 1) * 18 + i2] = ps[1];
          xT[(e4 + 2) * 18 + i2] = ps[2];
          xT[(e4 + 3) * 18 + i2] = ps[3];
          sta8(combN + (size_t)(r0 + i2) * EE + e4, p);
        }
        __syncthreads();
        if (tid < 512) {
          const int row = tid >> 1, half = tid & 1;
          sta8(combTN + (size_t)row * BB + r0 + half * 8,
               *(const u64*)(&xT[row * 18 + half * 8]));
          sta8(combTN + (size_t)row * BB + r0 + half * 8 + 4,
               *(const u64*)(&xT[row * 18 + half * 8 + 4]));
        }
      }
    }
    // ---- barrier between fused steps (not after last: dispatch boundary)
    if (k < NSTEP - 1) gbar64(flags, rel, wg, (unsigned)(bbase + k + 1));
  }
}

extern "C" void kernel_launch(void* const* d_in, const int* in_sizes, int n_in,
                              void* d_out, int out_size, void* d_ws, size_t ws_size,
                              hipStream_t stream) {
  const float* x   = (const float*)d_in[0];
  const float* Wq  = (const float*)d_in[1];
  const float* Wk  = (const float*)d_in[2];
  const float* Wv  = (const float*)d_in[3];
  const float* Wf  = (const float*)d_in[4];
  const float* bfv = (const float*)d_in[5];
  const float* Wi  = (const float*)d_in[6];
  const float* biv = (const float*)d_in[7];
  const float* Wgg = (const float*)d_in[8];
  const float* bgv = (const float*)d_in[9];
  const float* Wo  = (const float*)d_in[10];
  const float* bov = (const float*)d_in[11];
  float* out = (float*)d_out;
  char* wsb = (char*)d_ws;

  hipLaunchKernelGGL(qlstm_init_kernel, dim3(512), dim3(256), 0, stream,
                     x, Wq, Wk, Wv, Wf, Wi, Wgg, Wo, wsb);

  for (int d = 0; d < SEQ / NSTEP; ++d) {
    int t0 = d * NSTEP;
    int bbase = d * (NSTEP - 1);
    hipLaunchKernelGGL(qlstm_step_kernel, dim3(NWG), dim3(1024), 0, stream,
                       x, bfv, biv, bgv, bov, out, wsb, t0, bbase);
  }
}